// Round 18
// baseline (653.398 us; speedup 1.0000x reference)
//
#include <hip/hip_runtime.h>
#include <math.h>

#define N_NODES 20000
#define N_EDGES 640000
#define NZ 10
#define HD 128
#define NBESS 8
#define GS 16
#define TPS 132
#define NH (N_NODES*HD)
#define HH (HD*HD)
#define RMAXF 5.0f
#define PI_F 3.14159265358979323846f
#define C_PREF 0.6324555320336759f
#define SH_C0 0.2820947918f
#define SH_C1 0.4886025119f
#define SH_C2 1.0925484306f
#define SH_C6 0.3153915653f
#define SH_C8 0.5462742153f

typedef __attribute__((ext_vector_type(8))) short short8v;
typedef __attribute__((ext_vector_type(4))) float f32x4;

__device__ __forceinline__ float sigm(float x){ return 1.0f/(1.0f+expf(-x)); }
__device__ __forceinline__ unsigned short bf16r(float f){
  unsigned int u = __float_as_uint(f);
  unsigned int r = (u + 0x7fffu + ((u>>16)&1u))>>16;
  return (unsigned short)r;
}
__device__ __forceinline__ float bf2f(unsigned short h){ return __uint_as_float(((unsigned int)h)<<16); }

// ---------------- CSR build ----------------
__global__ void zeroi_k(int* __restrict__ p, int n){
  int i = blockIdx.x*256+threadIdx.x;
  if (i < n) p[i] = 0;
}
__global__ void hist_k(const int* __restrict__ srcI, const int* __restrict__ dstI,
                       int* __restrict__ cd, int* __restrict__ cs){
  int e = blockIdx.x*256+threadIdx.x;
  if (e >= N_EDGES) return;
  atomicAdd(&cd[dstI[e]], 1);
  atomicAdd(&cs[srcI[e]], 1);
}
__global__ void scan_k(const int* __restrict__ cnt2, int* __restrict__ rp2){
  const int* cnt = cnt2 + blockIdx.x*N_NODES;
  int* rp = rp2 + blockIdx.x*(N_NODES+1);
  __shared__ int part[1024];
  int t = threadIdx.x;
  const int CH = (N_NODES+1023)/1024;
  int base = t*CH, s = 0;
  for (int i=0;i<CH;i++){ int j=base+i; if (j<N_NODES) s += cnt[j]; }
  part[t] = s; __syncthreads();
  for (int off=1; off<1024; off<<=1){
    int v = (t>=off) ? part[t-off] : 0;
    __syncthreads();
    part[t] += v;
    __syncthreads();
  }
  int run = (t>0) ? part[t-1] : 0;
  for (int i=0;i<CH;i++){ int j=base+i; if (j<N_NODES){ rp[j]=run; run += cnt[j]; } }
  if (t==1023) rp[N_NODES] = part[1023];
}
__global__ void cpyi_k(const int* __restrict__ a, int* __restrict__ b, int n){
  int i = blockIdx.x*256+threadIdx.x;
  if (i < n) b[i] = a[i];
}

// ---------------- species from one-hot attrs ----------------
__global__ void species_k(const float* __restrict__ attrs, int* __restrict__ spec){
  int n = blockIdx.x*256+threadIdx.x;
  if (n >= N_NODES) return;
  const float* a = attrs + n*NZ;
  int sp = 0;
  #pragma unroll
  for (int z=0; z<NZ; z++) if (a[z] > 0.5f) sp = z;
  spec[n] = sp;
}

// T_P0[z][h] = sum_k Wemb[z][k]*Wmsg0[k][h];  T_sc[z][h] = sum_k Wemb[z][k]*Wsc0[k][h]
__global__ void tables_k(const float* __restrict__ Wemb, const float* __restrict__ Wmsg0,
                         const float* __restrict__ Wsc0,
                         float* __restrict__ T_P0, float* __restrict__ T_sc){
  int z = blockIdx.x, h = threadIdx.x;
  float accP = 0.f, accS = 0.f;
  for (int k=0; k<HD; k++){
    float w = Wemb[z*HD+k];
    accP += w*Wmsg0[k*HD+h];
    accS += w*Wsc0[k*HD+h];
  }
  T_P0[z*HD+h] = accP;
  T_sc[z*HD+h] = accS;
}

// ---------------- hi/lo bf16 split of {Wprod0,Wprod1,Wmsg1} in T and raw layouts ----------------
__global__ void wprep_k(const float* __restrict__ Wprod, const float* __restrict__ Wmsg,
                        unsigned short* __restrict__ Wb){
  int i = blockIdx.x*256+threadIdx.x;
  if (i >= 3*HH) return;
  int m = i/HH, r = i%HH;
  int k = r>>7, n = r&127;
  const float* src = (m==0) ? Wprod : (m==1) ? (Wprod+HH) : (Wmsg+HH);
  float f = src[r];
  unsigned short hi = bf16r(f);
  unsigned short lo = bf16r(f - bf2f(hi));
  Wb[((m*2+1)*2+0)*HH + r] = hi;
  Wb[((m*2+1)*2+1)*HH + r] = lo;
  Wb[((m*2+0)*2+0)*HH + n*HD + k] = hi;
  Wb[((m*2+0)*2+1)*HH + n*HD + k] = lo;
}

// ---------------- f32 -> bf16 shadow copy ----------------
__global__ void cvtbf_k(const float* __restrict__ in, unsigned short* __restrict__ out){
  int i = blockIdx.x*256+threadIdx.x;
  if (i >= NH/4) return;
  float4 v = *(const float4*)(in + 4*(size_t)i);
  unsigned short o0=bf16r(v.x), o1=bf16r(v.y), o2=bf16r(v.z), o3=bf16r(v.w);
  ushort2* p = (ushort2*)(out + 4*(size_t)i);
  p[0] = make_ushort2(o0,o1);
  p[1] = make_ushort2(o2,o3);
}

// ---------------- fused CSR-fill + geometry; row at dst-CSR pos; g[14]=s|sp<<15, g[15]=d ----------------
__global__ void geom_k(const float* __restrict__ pos, const float* __restrict__ shifts,
                       const int* __restrict__ srcI, const int* __restrict__ dstI,
                       int* __restrict__ curd, int* __restrict__ curs,
                       int2* __restrict__ pdS,
                       const int* __restrict__ spec,
                       const float* __restrict__ wsh, float* __restrict__ geom){
  int e = blockIdx.x*256+threadIdx.x;
  if (e >= N_EDGES) return;
  int s = srcI[e], d = dstI[e];
  int pd = atomicAdd(&curd[d],1);
  int ps = atomicAdd(&curs[s],1);
  pdS[ps] = make_int2(pd,d);
  float vx = pos[3*d+0]-pos[3*s+0]+shifts[3*e+0];
  float vy = pos[3*d+1]-pos[3*s+1]+shifts[3*e+1];
  float vz = pos[3*d+2]-pos[3*s+2]+shifts[3*e+2];
  float r = sqrtf(vx*vx+vy*vy+vz*vz+1e-12f);
  float inv = 1.0f/r;
  float x = vx*inv, y = vy*inv, z = vz*inv;
  float* g = geom + (size_t)pd*GS;
  g[0]=vx; g[1]=vy; g[2]=vz; g[3]=r;
  float theta = PI_F*r/RMAXF;
  float env = (r < RMAXF) ? 0.5f*(cosf(theta)+1.0f) : 0.0f;
  float s1 = sinf(theta), c1 = cosf(theta);
  float sn = s1, cn = c1;
  float pe = C_PREF*inv*env;
  #pragma unroll
  for (int n=0; n<NBESS; n++){
    g[4+n] = pe*sn;
    float sn2 = sn*c1 + cn*s1;
    float cn2 = cn*c1 - sn*s1;
    sn = sn2; cn = cn2;
  }
  float sh[9];
  sh[0] = SH_C0;
  sh[1] = SH_C1*y; sh[2] = SH_C1*z; sh[3] = SH_C1*x;
  sh[4] = SH_C2*x*y; sh[5] = SH_C2*y*z;
  sh[6] = SH_C6*(3.0f*z*z-1.0f);
  sh[7] = SH_C2*x*z; sh[8] = SH_C8*(x*x-y*y);
  float s0v=0.f, s1v=0.f;
  #pragma unroll
  for (int i=0;i<9;i++){ s0v += sh[i]*wsh[i]; s1v += sh[i]*wsh[9+i]; }
  g[12]=s0v; g[13]=s1v;
  g[14]=__int_as_float(s | (spec[s]<<15));
  g[15]=__int_as_float(d);
}

// g2vec = scale*W_read[1] ;  gh1c = scale*(W_read[0] + W_read[1] @ W_sc[1]^T)
__global__ void consts_k(const float* __restrict__ Wread, const float* __restrict__ Wsc,
                         const float* __restrict__ scalep,
                         float* __restrict__ g2vec, float* __restrict__ gh1c){
  int h = threadIdx.x;
  float sc = scalep[0];
  g2vec[h] = sc*Wread[HD+h];
  float acc = Wread[h];
  for (int j=0; j<HD; j++) acc += Wread[HD+j]*Wsc[HH + h*HD + j];
  gh1c[h] = sc*acc;
}

// ---------------- MFMA split-bf16 GEMM ----------------
__global__ __launch_bounds__(256) void gemmM_k(const float* __restrict__ A,
        const unsigned short* __restrict__ BThi, const unsigned short* __restrict__ BTlo,
        float* __restrict__ C, const float* __restrict__ addvec){
  int w = threadIdx.x>>6, l = threadIdx.x&63;
  int row0 = blockIdx.x*32 + (w&1)*16;
  int col0 = (w>>1)*64;
  int lrow = l&15, lk8 = (l>>4)*8;
  f32x4 acc[4];
  #pragma unroll
  for (int t=0;t<4;t++) acc[t] = (f32x4){0.f,0.f,0.f,0.f};
  for (int ks=0; ks<4; ks++){
    const float* ap = A + (size_t)(row0+lrow)*HD + ks*32 + lk8;
    float4 a01 = *(const float4*)ap;
    float4 a23 = *(const float4*)(ap+4);
    float av[8] = {a01.x,a01.y,a01.z,a01.w,a23.x,a23.y,a23.z,a23.w};
    short8v ahi, alo;
    #pragma unroll
    for (int j=0;j<8;j++){
      unsigned short hb = bf16r(av[j]);
      ahi[j] = (short)hb;
      alo[j] = (short)bf16r(av[j] - bf2f(hb));
    }
    #pragma unroll
    for (int t=0;t<4;t++){
      size_t boff = (size_t)(col0 + t*16 + lrow)*HD + ks*32 + lk8;
      short8v bhi = *(const short8v*)(BThi + boff);
      short8v blo = *(const short8v*)(BTlo + boff);
      acc[t] = __builtin_amdgcn_mfma_f32_16x16x32_bf16(ahi, bhi, acc[t], 0,0,0);
      acc[t] = __builtin_amdgcn_mfma_f32_16x16x32_bf16(ahi, blo, acc[t], 0,0,0);
      acc[t] = __builtin_amdgcn_mfma_f32_16x16x32_bf16(alo, bhi, acc[t], 0,0,0);
    }
  }
  #pragma unroll
  for (int t=0;t<4;t++){
    int col = col0 + t*16 + lrow;
    float av = addvec ? addvec[col] : 0.f;
    #pragma unroll
    for (int r=0;r<4;r++){
      int rr = row0 + (l>>4)*4 + r;
      C[(size_t)rr*HD + col] = acc[t][r] + av;
    }
  }
}

// h1 = silu(z0) + T_sc[spec[n]]
__global__ void h1_k(const float* __restrict__ z, const int* __restrict__ spec,
                     const float* __restrict__ T_sc, float* __restrict__ h){
  int i = blockIdx.x*256+threadIdx.x;
  if (i >= NH) return;
  int n = i>>7, hh = i&127;
  float x = z[i];
  h[i] = x*sigm(x) + T_sc[spec[n]*HD+hh];
}

__global__ void dzb_k(const float* __restrict__ z, const float* __restrict__ gvecc,
                      float* __restrict__ dz){
  int i = blockIdx.x*256+threadIdx.x;
  if (i >= NH) return;
  float x = z[i]; float sg = sigm(x);
  dz[i] = gvecc[i&127]*sg*(1.0f + x*(1.0f-sg));
}

__global__ void dzf_k(const float* __restrict__ z, const float* __restrict__ gh,
                      float* __restrict__ dz){
  int i = blockIdx.x*256+threadIdx.x;
  if (i >= NH) return;
  float x = z[i]; float sg = sigm(x);
  dz[i] = gh[i]*sg*(1.0f + x*(1.0f-sg));
}

__device__ __forceinline__ float dot8(float4 ra, float4 rb, const float* w){
  return ra.x*w[0]+ra.y*w[1]+ra.z*w[2]+ra.w*w[3]+rb.x*w[4]+rb.y*w[5]+rb.z*w[6]+rb.w*w[7];
}

// ---------------- layer-0 dst gather: rows from 10-entry LDS table, 4x unroll ----------------
__global__ __launch_bounds__(256) void gatherD0_k(const float* __restrict__ geom,
        const int* __restrict__ rp, const float* __restrict__ T_P0,
        const float* __restrict__ Wrad, float* __restrict__ out){
  __shared__ float tp[NZ*TPS];
  for (int i=threadIdx.x; i<NZ*HD; i+=256){ int z=i>>7, h=i&127; tp[z*TPS+h]=T_P0[i]; }
  __syncthreads();
  int wave = threadIdx.x>>6, lane = threadIdx.x&63;
  int node = blockIdx.x*4 + wave;
  float wv0[NBESS], wv1[NBESS];
  #pragma unroll
  for (int n=0;n<NBESS;n++){ wv0[n]=Wrad[n*HD+lane]; wv1[n]=Wrad[n*HD+64+lane]; }
  int b = rp[node], en = rp[node+1];
  float acc0 = 0.f, acc1 = 0.f;
  int i = b;
  for (; i+4 <= en; i+=4){
    const float* g0=geom+(size_t)(i+0)*GS; const float* g1=geom+(size_t)(i+1)*GS;
    const float* g2=geom+(size_t)(i+2)*GS; const float* g3=geom+(size_t)(i+3)*GS;
    float4 ra0=*(const float4*)(g0+4), rb0=*(const float4*)(g0+8);
    float4 ra1=*(const float4*)(g1+4), rb1=*(const float4*)(g1+8);
    float4 ra2=*(const float4*)(g2+4), rb2=*(const float4*)(g2+8);
    float4 ra3=*(const float4*)(g3+4), rb3=*(const float4*)(g3+8);
    float s0=g0[12], s1=g1[12], s2=g2[12], s3=g3[12];
    int sp0=__float_as_int(g0[14])>>15, sp1=__float_as_int(g1[14])>>15;
    int sp2=__float_as_int(g2[14])>>15, sp3=__float_as_int(g3[14])>>15;
    acc0 += tp[sp0*TPS+lane]*(s0*dot8(ra0,rb0,wv0));  acc1 += tp[sp0*TPS+64+lane]*(s0*dot8(ra0,rb0,wv1));
    acc0 += tp[sp1*TPS+lane]*(s1*dot8(ra1,rb1,wv0));  acc1 += tp[sp1*TPS+64+lane]*(s1*dot8(ra1,rb1,wv1));
    acc0 += tp[sp2*TPS+lane]*(s2*dot8(ra2,rb2,wv0));  acc1 += tp[sp2*TPS+64+lane]*(s2*dot8(ra2,rb2,wv1));
    acc0 += tp[sp3*TPS+lane]*(s3*dot8(ra3,rb3,wv0));  acc1 += tp[sp3*TPS+64+lane]*(s3*dot8(ra3,rb3,wv1));
  }
  for (; i<en; i++){
    const float* g = geom + (size_t)i*GS;
    float4 ra = *(const float4*)(g+4);
    float4 rb = *(const float4*)(g+8);
    float shs = g[12];
    int sp = __float_as_int(g[14]) >> 15;
    acc0 += tp[sp*TPS+lane]    * (shs*dot8(ra,rb,wv0));
    acc1 += tp[sp*TPS+64+lane] * (shs*dot8(ra,rb,wv1));
  }
  out[(size_t)node*HD+lane]    = acc0;
  out[(size_t)node*HD+64+lane] = acc1;
}

// ---------------- layer-1 dst gather (P1 rows random, bf16), 4x unroll; src from geom ----------------
__global__ __launch_bounds__(256) void gatherD_k(const float* __restrict__ geom,
        const int* __restrict__ rp,
        const unsigned short* __restrict__ rowsb,
        const float* __restrict__ Wrad, int shsOff, float* __restrict__ out){
  int wave = threadIdx.x>>6, lane = threadIdx.x&63;
  int node = blockIdx.x*4 + wave;
  float wv0[NBESS], wv1[NBESS];
  #pragma unroll
  for (int n=0;n<NBESS;n++){ wv0[n]=Wrad[n*HD+lane]; wv1[n]=Wrad[n*HD+64+lane]; }
  int b = rp[node], en = rp[node+1];
  float acc0 = 0.f, acc1 = 0.f;
  int i = b;
  for (; i+4 <= en; i+=4){
    const float* g0=geom+(size_t)(i+0)*GS; const float* g1=geom+(size_t)(i+1)*GS;
    const float* g2=geom+(size_t)(i+2)*GS; const float* g3=geom+(size_t)(i+3)*GS;
    int o0=__float_as_int(g0[14])&0x7FFF, o1=__float_as_int(g1[14])&0x7FFF;
    int o2=__float_as_int(g2[14])&0x7FFF, o3=__float_as_int(g3[14])&0x7FFF;
    float4 ra0=*(const float4*)(g0+4), rb0=*(const float4*)(g0+8);
    float4 ra1=*(const float4*)(g1+4), rb1=*(const float4*)(g1+8);
    float4 ra2=*(const float4*)(g2+4), rb2=*(const float4*)(g2+8);
    float4 ra3=*(const float4*)(g3+4), rb3=*(const float4*)(g3+8);
    float s0=g0[shsOff], s1=g1[shsOff], s2=g2[shsOff], s3=g3[shsOff];
    float p00=bf2f(rowsb[(size_t)o0*HD+lane]), p01=bf2f(rowsb[(size_t)o0*HD+64+lane]);
    float p10=bf2f(rowsb[(size_t)o1*HD+lane]), p11=bf2f(rowsb[(size_t)o1*HD+64+lane]);
    float p20=bf2f(rowsb[(size_t)o2*HD+lane]), p21=bf2f(rowsb[(size_t)o2*HD+64+lane]);
    float p30=bf2f(rowsb[(size_t)o3*HD+lane]), p31=bf2f(rowsb[(size_t)o3*HD+64+lane]);
    acc0 += p00*(s0*dot8(ra0,rb0,wv0));  acc1 += p01*(s0*dot8(ra0,rb0,wv1));
    acc0 += p10*(s1*dot8(ra1,rb1,wv0));  acc1 += p11*(s1*dot8(ra1,rb1,wv1));
    acc0 += p20*(s2*dot8(ra2,rb2,wv0));  acc1 += p21*(s2*dot8(ra2,rb2,wv1));
    acc0 += p30*(s3*dot8(ra3,rb3,wv0));  acc1 += p31*(s3*dot8(ra3,rb3,wv1));
  }
  for (; i<en; i++){
    const float* g = geom + (size_t)i*GS;
    int o = __float_as_int(g[14])&0x7FFF;
    float4 ra = *(const float4*)(g+4);
    float4 rb = *(const float4*)(g+8);
    float shs = g[shsOff];
    acc0 += bf2f(rowsb[(size_t)o*HD+lane])    * (shs*dot8(ra,rb,wv0));
    acc1 += bf2f(rowsb[(size_t)o*HD+64+lane]) * (shs*dot8(ra,rb,wv1));
  }
  out[(size_t)node*HD+lane]    = acc0;
  out[(size_t)node*HD+64+lane] = acc1;
}

// ---------------- src-keyed gather (backward A1, bf16 rows), 4x unroll ----------------
__global__ __launch_bounds__(256) void gatherS_k(const float* __restrict__ geom,
        const int* __restrict__ rp, const int2* __restrict__ pdS,
        const unsigned short* __restrict__ rowsb,
        const float* __restrict__ Wrad, int shsOff, float* __restrict__ out){
  int wave = threadIdx.x>>6, lane = threadIdx.x&63;
  int node = blockIdx.x*4 + wave;
  float wv0[NBESS], wv1[NBESS];
  #pragma unroll
  for (int n=0;n<NBESS;n++){ wv0[n]=Wrad[n*HD+lane]; wv1[n]=Wrad[n*HD+64+lane]; }
  int b = rp[node], en = rp[node+1];
  float acc0 = 0.f, acc1 = 0.f;
  int i = b;
  for (; i+4 <= en; i+=4){
    int2 t0=pdS[i+0], t1=pdS[i+1], t2=pdS[i+2], t3=pdS[i+3];
    const float* g0=geom+(size_t)t0.x*GS; const float* g1=geom+(size_t)t1.x*GS;
    const float* g2=geom+(size_t)t2.x*GS; const float* g3=geom+(size_t)t3.x*GS;
    float4 ra0=*(const float4*)(g0+4), rb0=*(const float4*)(g0+8);
    float4 ra1=*(const float4*)(g1+4), rb1=*(const float4*)(g1+8);
    float4 ra2=*(const float4*)(g2+4), rb2=*(const float4*)(g2+8);
    float4 ra3=*(const float4*)(g3+4), rb3=*(const float4*)(g3+8);
    float s0=g0[shsOff], s1=g1[shsOff], s2=g2[shsOff], s3=g3[shsOff];
    float p00=bf2f(rowsb[(size_t)t0.y*HD+lane]), p01=bf2f(rowsb[(size_t)t0.y*HD+64+lane]);
    float p10=bf2f(rowsb[(size_t)t1.y*HD+lane]), p11=bf2f(rowsb[(size_t)t1.y*HD+64+lane]);
    float p20=bf2f(rowsb[(size_t)t2.y*HD+lane]), p21=bf2f(rowsb[(size_t)t2.y*HD+64+lane]);
    float p30=bf2f(rowsb[(size_t)t3.y*HD+lane]), p31=bf2f(rowsb[(size_t)t3.y*HD+64+lane]);
    acc0 += p00*(s0*dot8(ra0,rb0,wv0));  acc1 += p01*(s0*dot8(ra0,rb0,wv1));
    acc0 += p10*(s1*dot8(ra1,rb1,wv0));  acc1 += p11*(s1*dot8(ra1,rb1,wv1));
    acc0 += p20*(s2*dot8(ra2,rb2,wv0));  acc1 += p21*(s2*dot8(ra2,rb2,wv1));
    acc0 += p30*(s3*dot8(ra3,rb3,wv0));  acc1 += p31*(s3*dot8(ra3,rb3,wv1));
  }
  for (; i<en; i++){
    int2 t = pdS[i];
    const float* g = geom + (size_t)t.x*GS;
    float4 ra = *(const float4*)(g+4);
    float4 rb = *(const float4*)(g+8);
    float shs = g[shsOff];
    acc0 += bf2f(rowsb[(size_t)t.y*HD+lane])    * (shs*dot8(ra,rb,wv0));
    acc1 += bf2f(rowsb[(size_t)t.y*HD+64+lane]) * (shs*dot8(ra,rb,wv1));
  }
  out[(size_t)node*HD+lane]    = acc0;
  out[(size_t)node*HD+64+lane] = acc1;
}

// ---------------- fused two-layer qdot; weights in LDS; indices from geom ----------------
__global__ __launch_bounds__(256) void qdotF_k(const float* __restrict__ geom,
        const float* __restrict__ G1, const float* __restrict__ P1,
        const float* __restrict__ G0, const float* __restrict__ T_P0,
        const float* __restrict__ Wrad, const float* __restrict__ wshp,
        float* __restrict__ gvec){
  __shared__ float wr0[NBESS*HD];
  __shared__ float wr1[NBESS*HD];
  __shared__ float tp0[NZ*TPS];
  __shared__ float ws[18];
  for (int i=threadIdx.x; i<NBESS*HD; i+=256){ wr0[i]=Wrad[i]; wr1[i]=Wrad[NBESS*HD+i]; }
  for (int i=threadIdx.x; i<NZ*HD; i+=256){ int z=i>>7, h=i&127; tp0[z*TPS+h]=T_P0[i]; }
  if (threadIdx.x < 18) ws[threadIdx.x] = wshp[threadIdx.x];
  __syncthreads();
  int i = blockIdx.x*256+threadIdx.x;
  const float* g = geom + (size_t)i*GS;
  int g14 = __float_as_int(g[14]);
  int s = g14 & 0x7FFF, sp = g14 >> 15;
  int d = __float_as_int(g[15]);
  const float4* G1r = (const float4*)(G1 + (size_t)d*HD);
  const float4* P1r = (const float4*)(P1 + (size_t)s*HD);
  const float4* G0r = (const float4*)(G0 + (size_t)d*HD);
  const float* P0l = tp0 + sp*TPS;
  float gr80[NBESS] = {0,0,0,0,0,0,0,0};
  float gr81[NBESS] = {0,0,0,0,0,0,0,0};
  #pragma unroll 2
  for (int k=0; k<32; k++){
    float4 g1q = G1r[k], p1q = P1r[k];
    float4 g0q = G0r[k];
    float4 p0q = *(const float4*)&P0l[4*k];
    float a0 = g1q.x*p1q.x, a1 = g1q.y*p1q.y, a2 = g1q.z*p1q.z, a3 = g1q.w*p1q.w;
    float b0 = g0q.x*p0q.x, b1 = g0q.y*p0q.y, b2 = g0q.z*p0q.z, b3 = g0q.w*p0q.w;
    #pragma unroll
    for (int n=0; n<NBESS; n++){
      const float4 w1 = *(const float4*)&wr1[n*HD + 4*k];
      const float4 w0 = *(const float4*)&wr0[n*HD + 4*k];
      gr81[n] += a0*w1.x + a1*w1.y + a2*w1.z + a3*w1.w;
      gr80[n] += b0*w0.x + b1*w0.y + b2*w0.z + b3*w0.w;
    }
  }
  float vx=g[0], vy=g[1], vz=g[2], r=g[3];
  float shs0 = g[12], shs1 = g[13];
  float gshs0 = 0.f, gshs1 = 0.f;
  float grd[NBESS];
  #pragma unroll
  for (int n=0; n<NBESS; n++){
    float rn = g[4+n];
    gshs0 += rn*gr80[n];
    gshs1 += rn*gr81[n];
    grd[n] = shs0*gr80[n] + shs1*gr81[n];
  }
  float inv = 1.0f/r;
  float x = vx*inv, y = vy*inv, z = vz*inv;
  float gs1=gshs0*ws[1]+gshs1*ws[10], gs2=gshs0*ws[2]+gshs1*ws[11];
  float gs3=gshs0*ws[3]+gshs1*ws[12], gs4=gshs0*ws[4]+gshs1*ws[13];
  float gs5=gshs0*ws[5]+gshs1*ws[14], gs6=gshs0*ws[6]+gshs1*ws[15];
  float gs7=gshs0*ws[7]+gshs1*ws[16], gs8=gshs0*ws[8]+gshs1*ws[17];
  float gux = SH_C1*gs3 + SH_C2*(y*gs4 + z*gs7) + 1.0925484306f*x*gs8;
  float guy = SH_C1*gs1 + SH_C2*(x*gs4 + z*gs5) - 1.0925484306f*y*gs8;
  float guz = SH_C1*gs2 + SH_C2*(y*gs5 + x*gs7) + 1.8923493918f*z*gs6;
  float udot = x*gux + y*guy + z*guz;
  float gr = 0.f;
  if (r < RMAXF){
    float theta = PI_F*r/RMAXF;
    float s1 = sinf(theta), c1 = cosf(theta);
    float env  = 0.5f*(c1+1.0f);
    float denv = -0.5f*(PI_F/RMAXF)*s1;
    float sn = s1, cn = c1;
    #pragma unroll
    for (int n=0; n<NBESS; n++){
      float an = (float)(n+1)*(PI_F/RMAXF);
      float bess  = C_PREF*sn*inv;
      float dbess = C_PREF*inv*(an*cn - sn*inv);
      gr += grd[n]*(dbess*env + bess*denv);
      float sn2 = sn*c1 + cn*s1;
      float cn2 = cn*c1 - sn*s1;
      sn = sn2; cn = cn2;
    }
  }
  gvec[3*(size_t)i+0] = gr*x + (gux - x*udot)*inv;
  gvec[3*(size_t)i+1] = gr*y + (guy - y*udot)*inv;
  gvec[3*(size_t)i+2] = gr*z + (guz - z*udot)*inv;
}

// ---------------- F[n] = sum_out gvec - sum_in gvec (gvec at dst-CSR pos) ----------------
__global__ __launch_bounds__(256) void fgather_k(const int* __restrict__ rpd,
        const int* __restrict__ rps, const int2* __restrict__ pdS,
        const float* __restrict__ gvec, float* __restrict__ F){
  int wave = threadIdx.x>>6, lane = threadIdx.x&63;
  int n = blockIdx.x*4 + wave;
  float fx=0.f, fy=0.f, fz=0.f;
  int b=rps[n], en=rps[n+1];
  for (int i=b+lane; i<en; i+=64){ int j=pdS[i].x; fx+=gvec[3*(size_t)j]; fy+=gvec[3*(size_t)j+1]; fz+=gvec[3*(size_t)j+2]; }
  b=rpd[n]; en=rpd[n+1];
  for (int i=b+lane; i<en; i+=64){ fx-=gvec[3*(size_t)i]; fy-=gvec[3*(size_t)i+1]; fz-=gvec[3*(size_t)i+2]; }
  #pragma unroll
  for (int off=1; off<64; off<<=1){
    fx += __shfl_xor(fx, off);
    fy += __shfl_xor(fy, off);
    fz += __shfl_xor(fz, off);
  }
  if (lane==0){ F[3*(size_t)n]=fx; F[3*(size_t)n+1]=fy; F[3*(size_t)n+2]=fz; }
}

extern "C" void kernel_launch(void* const* d_in, const int* in_sizes, int n_in,
                              void* d_out, int out_size, void* d_ws, size_t ws_size,
                              hipStream_t stream){
  const float* pos    = (const float*)d_in[0];
  const float* attrs  = (const float*)d_in[1];
  const float* shifts = (const float*)d_in[2];
  const float* Wemb   = (const float*)d_in[4];
  const float* Wmsg   = (const float*)d_in[5];
  const float* Wrad   = (const float*)d_in[6];
  const float* wsh    = (const float*)d_in[7];
  const float* Wprod  = (const float*)d_in[8];
  const float* Wsc    = (const float*)d_in[9];
  const float* Wread  = (const float*)d_in[10];
  const float* scalep = (const float*)d_in[11];
  const int*   eidx   = (const int*)d_in[13];
  const int* srcI = eidx;
  const int* dstI = eidx + N_EDGES;
  float* F = (float*)d_out;
  (void)ws_size; (void)in_sizes; (void)n_in; (void)out_size;

  float* w = (float*)d_ws;
  size_t off = 0;
  auto alloc = [&](size_t nf){ float* p = w + off; off += nf; return p; };
  float* geom = alloc((size_t)N_EDGES*GS);
  float* h1   = alloc(NH);
  float* P1   = alloc(NH);
  float* z0   = alloc(NH);
  float* z1   = alloc(NH);
  float* Svar = alloc(NH);
  float* agg  = alloc(NH);
  float* Gbuf1= alloc(NH);
  float* Gbuf0= alloc(NH);
  float* A1   = alloc(NH);
  float* gh1  = alloc(NH);
  float* T_P0 = alloc(NZ*HD);
  float* T_sc = alloc(NZ*HD);
  float* g2vec = alloc(HD);
  float* gh1c  = alloc(HD);
  float* gvec  = alloc((size_t)N_EDGES*3);
  unsigned short* Wb  = (unsigned short*)alloc(6*HH);
  unsigned short* P1b = (unsigned short*)alloc(NH/2);
  unsigned short* G1b = (unsigned short*)alloc(NH/2);
  int* ibase = (int*)(w + off);
  int* cnt2 = ibase;                        // 2*N
  int* rp2  = ibase + 2*N_NODES;            // 2*(N+1)
  int* cur2 = rp2 + 2*(N_NODES+1);          // 2*(N+1)
  int* spec = cur2 + 2*(N_NODES+1);         // N
  int2* pdS = (int2*)(((size_t)(spec + N_NODES) + 7) & ~(size_t)7); // E int2
  int* rpd = rp2;
  int* rps = rp2 + (N_NODES+1);
  int* curd = cur2;
  int* curs = cur2 + (N_NODES+1);

  const unsigned short* Wp0T_h = Wb + 0*HH; const unsigned short* Wp0T_l = Wb + 1*HH;
  const unsigned short* Wp0R_h = Wb + 2*HH; const unsigned short* Wp0R_l = Wb + 3*HH;
  const unsigned short* Wp1T_h = Wb + 4*HH; const unsigned short* Wp1T_l = Wb + 5*HH;
  const unsigned short* Wp1R_h = Wb + 6*HH; const unsigned short* Wp1R_l = Wb + 7*HH;
  const unsigned short* Wm1T_h = Wb + 8*HH; const unsigned short* Wm1T_l = Wb + 9*HH;
  const unsigned short* Wm1R_h = Wb +10*HH; const unsigned short* Wm1R_l = Wb +11*HH;

  const int GEMM_GRID = N_NODES/32;    // 625
  const int NODE_GRID = N_NODES/4;     // 5000
  const int E_GRID    = N_EDGES/256;   // 2500
  const int CVT_GRID  = (NH/4+255)/256;

  // CSR build
  zeroi_k<<<(2*N_NODES+255)/256, 256, 0, stream>>>(cnt2, 2*N_NODES);
  hist_k<<<E_GRID, 256, 0, stream>>>(srcI, dstI, cnt2, cnt2+N_NODES);
  scan_k<<<2, 1024, 0, stream>>>(cnt2, rp2);
  cpyi_k<<<(2*(N_NODES+1)+255)/256, 256, 0, stream>>>(rp2, cur2, 2*(N_NODES+1));

  species_k<<<(N_NODES+255)/256, 256, 0, stream>>>(attrs, spec);
  geom_k<<<E_GRID, 256, 0, stream>>>(pos, shifts, srcI, dstI, curd, curs, pdS, spec, wsh, geom);
  tables_k<<<NZ, HD, 0, stream>>>(Wemb, Wmsg, Wsc, T_P0, T_sc);
  wprep_k<<<(3*HH+255)/256, 256, 0, stream>>>(Wprod, Wmsg, (unsigned short*)Wb);
  consts_k<<<1, HD, 0, stream>>>(Wread, Wsc, scalep, g2vec, gh1c);

  // ---- layer 0 forward (P0/sc0 via species tables) ----
  gatherD0_k<<<NODE_GRID, 256, 0, stream>>>(geom, rpd, T_P0, Wrad, agg);
  gemmM_k<<<GEMM_GRID, 256, 0, stream>>>(agg, Wp0T_h, Wp0T_l, z0, nullptr);
  h1_k<<<NH/256, 256, 0, stream>>>(z0, spec, T_sc, h1);

  // ---- layer 1 forward ----
  gemmM_k<<<GEMM_GRID, 256, 0, stream>>>(h1, Wm1T_h, Wm1T_l, P1, nullptr);
  cvtbf_k<<<CVT_GRID, 256, 0, stream>>>(P1, P1b);
  gatherD_k<<<NODE_GRID, 256, 0, stream>>>(geom, rpd, P1b, Wrad+NBESS*HD, 13, agg);
  gemmM_k<<<GEMM_GRID, 256, 0, stream>>>(agg, Wp1T_h, Wp1T_l, z1, nullptr);

  // ---- backward ----
  dzb_k<<<NH/256, 256, 0, stream>>>(z1, g2vec, Svar);
  gemmM_k<<<GEMM_GRID, 256, 0, stream>>>(Svar, Wp1R_h, Wp1R_l, Gbuf1, nullptr);
  cvtbf_k<<<CVT_GRID, 256, 0, stream>>>(Gbuf1, G1b);
  gatherS_k<<<NODE_GRID, 256, 0, stream>>>(geom, rps, pdS, G1b, Wrad+NBESS*HD, 13, A1);
  gemmM_k<<<GEMM_GRID, 256, 0, stream>>>(A1, Wm1R_h, Wm1R_l, gh1, gh1c);
  dzf_k<<<NH/256, 256, 0, stream>>>(z0, gh1, Svar);
  gemmM_k<<<GEMM_GRID, 256, 0, stream>>>(Svar, Wp0R_h, Wp0R_l, Gbuf0, nullptr);
  qdotF_k<<<E_GRID, 256, 0, stream>>>(geom, Gbuf1, P1, Gbuf0, T_P0, Wrad, wsh, gvec);
  fgather_k<<<NODE_GRID, 256, 0, stream>>>(rpd, rps, pdS, gvec, F);
}

// Round 19
// 628.900 us; speedup vs baseline: 1.0390x; 1.0390x over previous
//
#include <hip/hip_runtime.h>
#include <math.h>

#define N_NODES 20000
#define N_EDGES 640000
#define NZ 10
#define HD 128
#define NBESS 8
#define GS 16
#define TPS 132
#define NH (N_NODES*HD)
#define HH (HD*HD)
#define RMAXF 5.0f
#define PI_F 3.14159265358979323846f
#define C_PREF 0.6324555320336759f
#define SH_C0 0.2820947918f
#define SH_C1 0.4886025119f
#define SH_C2 1.0925484306f
#define SH_C6 0.3153915653f
#define SH_C8 0.5462742153f

typedef __attribute__((ext_vector_type(8))) short short8v;
typedef __attribute__((ext_vector_type(4))) float f32x4;

__device__ __forceinline__ float sigm(float x){ return 1.0f/(1.0f+expf(-x)); }
__device__ __forceinline__ unsigned short bf16r(float f){
  unsigned int u = __float_as_uint(f);
  unsigned int r = (u + 0x7fffu + ((u>>16)&1u))>>16;
  return (unsigned short)r;
}
__device__ __forceinline__ float bf2f(unsigned short h){ return __uint_as_float(((unsigned int)h)<<16); }

// ---------------- CSR build ----------------
__global__ void zeroi_k(int* __restrict__ p, int n){
  int i = blockIdx.x*256+threadIdx.x;
  if (i < n) p[i] = 0;
}
__global__ void hist_k(const int* __restrict__ srcI, const int* __restrict__ dstI,
                       int* __restrict__ cd, int* __restrict__ cs){
  int e = blockIdx.x*256+threadIdx.x;
  if (e >= N_EDGES) return;
  atomicAdd(&cd[dstI[e]], 1);
  atomicAdd(&cs[srcI[e]], 1);
}
__global__ void scan_k(const int* __restrict__ cnt2, int* __restrict__ rp2){
  const int* cnt = cnt2 + blockIdx.x*N_NODES;
  int* rp = rp2 + blockIdx.x*(N_NODES+1);
  __shared__ int part[1024];
  int t = threadIdx.x;
  const int CH = (N_NODES+1023)/1024;
  int base = t*CH, s = 0;
  for (int i=0;i<CH;i++){ int j=base+i; if (j<N_NODES) s += cnt[j]; }
  part[t] = s; __syncthreads();
  for (int off=1; off<1024; off<<=1){
    int v = (t>=off) ? part[t-off] : 0;
    __syncthreads();
    part[t] += v;
    __syncthreads();
  }
  int run = (t>0) ? part[t-1] : 0;
  for (int i=0;i<CH;i++){ int j=base+i; if (j<N_NODES){ rp[j]=run; run += cnt[j]; } }
  if (t==1023) rp[N_NODES] = part[1023];
}
__global__ void cpyi_k(const int* __restrict__ a, int* __restrict__ b, int n){
  int i = blockIdx.x*256+threadIdx.x;
  if (i < n) b[i] = a[i];
}

// ---------------- species from one-hot attrs ----------------
__global__ void species_k(const float* __restrict__ attrs, int* __restrict__ spec){
  int n = blockIdx.x*256+threadIdx.x;
  if (n >= N_NODES) return;
  const float* a = attrs + n*NZ;
  int sp = 0;
  #pragma unroll
  for (int z=0; z<NZ; z++) if (a[z] > 0.5f) sp = z;
  spec[n] = sp;
}

// T_P0[z][h] = sum_k Wemb[z][k]*Wmsg0[k][h];  T_sc[z][h] = sum_k Wemb[z][k]*Wsc0[k][h]
__global__ void tables_k(const float* __restrict__ Wemb, const float* __restrict__ Wmsg0,
                         const float* __restrict__ Wsc0,
                         float* __restrict__ T_P0, float* __restrict__ T_sc){
  int z = blockIdx.x, h = threadIdx.x;
  float accP = 0.f, accS = 0.f;
  for (int k=0; k<HD; k++){
    float w = Wemb[z*HD+k];
    accP += w*Wmsg0[k*HD+h];
    accS += w*Wsc0[k*HD+h];
  }
  T_P0[z*HD+h] = accP;
  T_sc[z*HD+h] = accS;
}

// ---------------- hi/lo bf16 split of {Wprod0,Wprod1,Wmsg1} in T and raw layouts ----------------
__global__ void wprep_k(const float* __restrict__ Wprod, const float* __restrict__ Wmsg,
                        unsigned short* __restrict__ Wb){
  int i = blockIdx.x*256+threadIdx.x;
  if (i >= 3*HH) return;
  int m = i/HH, r = i%HH;
  int k = r>>7, n = r&127;
  const float* src = (m==0) ? Wprod : (m==1) ? (Wprod+HH) : (Wmsg+HH);
  float f = src[r];
  unsigned short hi = bf16r(f);
  unsigned short lo = bf16r(f - bf2f(hi));
  Wb[((m*2+1)*2+0)*HH + r] = hi;
  Wb[((m*2+1)*2+1)*HH + r] = lo;
  Wb[((m*2+0)*2+0)*HH + n*HD + k] = hi;
  Wb[((m*2+0)*2+1)*HH + n*HD + k] = lo;
}

// ---------------- fused CSR-fill + geometry; row at dst-CSR pos; g[14]=s|sp<<15, g[15]=d ----------------
__global__ void geom_k(const float* __restrict__ pos, const float* __restrict__ shifts,
                       const int* __restrict__ srcI, const int* __restrict__ dstI,
                       int* __restrict__ curd, int* __restrict__ curs,
                       int2* __restrict__ pdS,
                       const int* __restrict__ spec,
                       const float* __restrict__ wsh, float* __restrict__ geom){
  int e = blockIdx.x*256+threadIdx.x;
  if (e >= N_EDGES) return;
  int s = srcI[e], d = dstI[e];
  int pd = atomicAdd(&curd[d],1);
  int ps = atomicAdd(&curs[s],1);
  pdS[ps] = make_int2(pd,d);
  float vx = pos[3*d+0]-pos[3*s+0]+shifts[3*e+0];
  float vy = pos[3*d+1]-pos[3*s+1]+shifts[3*e+1];
  float vz = pos[3*d+2]-pos[3*s+2]+shifts[3*e+2];
  float r = sqrtf(vx*vx+vy*vy+vz*vz+1e-12f);
  float inv = 1.0f/r;
  float x = vx*inv, y = vy*inv, z = vz*inv;
  float* g = geom + (size_t)pd*GS;
  g[0]=vx; g[1]=vy; g[2]=vz; g[3]=r;
  float theta = PI_F*r/RMAXF;
  float env = (r < RMAXF) ? 0.5f*(cosf(theta)+1.0f) : 0.0f;
  float s1 = sinf(theta), c1 = cosf(theta);
  float sn = s1, cn = c1;
  float pe = C_PREF*inv*env;
  #pragma unroll
  for (int n=0; n<NBESS; n++){
    g[4+n] = pe*sn;
    float sn2 = sn*c1 + cn*s1;
    float cn2 = cn*c1 - sn*s1;
    sn = sn2; cn = cn2;
  }
  float sh[9];
  sh[0] = SH_C0;
  sh[1] = SH_C1*y; sh[2] = SH_C1*z; sh[3] = SH_C1*x;
  sh[4] = SH_C2*x*y; sh[5] = SH_C2*y*z;
  sh[6] = SH_C6*(3.0f*z*z-1.0f);
  sh[7] = SH_C2*x*z; sh[8] = SH_C8*(x*x-y*y);
  float s0v=0.f, s1v=0.f;
  #pragma unroll
  for (int i=0;i<9;i++){ s0v += sh[i]*wsh[i]; s1v += sh[i]*wsh[9+i]; }
  g[12]=s0v; g[13]=s1v;
  g[14]=__int_as_float(s | (spec[s]<<15));
  g[15]=__int_as_float(d);
}

// g2vec = scale*W_read[1] ;  gh1c = scale*(W_read[0] + W_read[1] @ W_sc[1]^T)
__global__ void consts_k(const float* __restrict__ Wread, const float* __restrict__ Wsc,
                         const float* __restrict__ scalep,
                         float* __restrict__ g2vec, float* __restrict__ gh1c){
  int h = threadIdx.x;
  float sc = scalep[0];
  g2vec[h] = sc*Wread[HD+h];
  float acc = Wread[h];
  for (int j=0; j<HD; j++) acc += Wread[HD+j]*Wsc[HH + h*HD + j];
  gh1c[h] = sc*acc;
}

// ---------------- MFMA split-bf16 GEMM ----------------
__global__ __launch_bounds__(256) void gemmM_k(const float* __restrict__ A,
        const unsigned short* __restrict__ BThi, const unsigned short* __restrict__ BTlo,
        float* __restrict__ C, const float* __restrict__ addvec){
  int w = threadIdx.x>>6, l = threadIdx.x&63;
  int row0 = blockIdx.x*32 + (w&1)*16;
  int col0 = (w>>1)*64;
  int lrow = l&15, lk8 = (l>>4)*8;
  f32x4 acc[4];
  #pragma unroll
  for (int t=0;t<4;t++) acc[t] = (f32x4){0.f,0.f,0.f,0.f};
  for (int ks=0; ks<4; ks++){
    const float* ap = A + (size_t)(row0+lrow)*HD + ks*32 + lk8;
    float4 a01 = *(const float4*)ap;
    float4 a23 = *(const float4*)(ap+4);
    float av[8] = {a01.x,a01.y,a01.z,a01.w,a23.x,a23.y,a23.z,a23.w};
    short8v ahi, alo;
    #pragma unroll
    for (int j=0;j<8;j++){
      unsigned short hb = bf16r(av[j]);
      ahi[j] = (short)hb;
      alo[j] = (short)bf16r(av[j] - bf2f(hb));
    }
    #pragma unroll
    for (int t=0;t<4;t++){
      size_t boff = (size_t)(col0 + t*16 + lrow)*HD + ks*32 + lk8;
      short8v bhi = *(const short8v*)(BThi + boff);
      short8v blo = *(const short8v*)(BTlo + boff);
      acc[t] = __builtin_amdgcn_mfma_f32_16x16x32_bf16(ahi, bhi, acc[t], 0,0,0);
      acc[t] = __builtin_amdgcn_mfma_f32_16x16x32_bf16(ahi, blo, acc[t], 0,0,0);
      acc[t] = __builtin_amdgcn_mfma_f32_16x16x32_bf16(alo, bhi, acc[t], 0,0,0);
    }
  }
  #pragma unroll
  for (int t=0;t<4;t++){
    int col = col0 + t*16 + lrow;
    float av = addvec ? addvec[col] : 0.f;
    #pragma unroll
    for (int r=0;r<4;r++){
      int rr = row0 + (l>>4)*4 + r;
      C[(size_t)rr*HD + col] = acc[t][r] + av;
    }
  }
}

// h1 = silu(z0) + T_sc[spec[n]]
__global__ void h1_k(const float* __restrict__ z, const int* __restrict__ spec,
                     const float* __restrict__ T_sc, float* __restrict__ h){
  int i = blockIdx.x*256+threadIdx.x;
  if (i >= NH) return;
  int n = i>>7, hh = i&127;
  float x = z[i];
  h[i] = x*sigm(x) + T_sc[spec[n]*HD+hh];
}

__global__ void dzb_k(const float* __restrict__ z, const float* __restrict__ gvecc,
                      float* __restrict__ dz){
  int i = blockIdx.x*256+threadIdx.x;
  if (i >= NH) return;
  float x = z[i]; float sg = sigm(x);
  dz[i] = gvecc[i&127]*sg*(1.0f + x*(1.0f-sg));
}

__global__ void dzf_k(const float* __restrict__ z, const float* __restrict__ gh,
                      float* __restrict__ dz){
  int i = blockIdx.x*256+threadIdx.x;
  if (i >= NH) return;
  float x = z[i]; float sg = sigm(x);
  dz[i] = gh[i]*sg*(1.0f + x*(1.0f-sg));
}

__device__ __forceinline__ float dot8(float4 ra, float4 rb, const float* w){
  return ra.x*w[0]+ra.y*w[1]+ra.z*w[2]+ra.w*w[3]+rb.x*w[4]+rb.y*w[5]+rb.z*w[6]+rb.w*w[7];
}

// ---------------- layer-0 dst gather: rows from 10-entry LDS table, 4x unroll ----------------
__global__ __launch_bounds__(256) void gatherD0_k(const float* __restrict__ geom,
        const int* __restrict__ rp, const float* __restrict__ T_P0,
        const float* __restrict__ Wrad, float* __restrict__ out){
  __shared__ float tp[NZ*TPS];
  for (int i=threadIdx.x; i<NZ*HD; i+=256){ int z=i>>7, h=i&127; tp[z*TPS+h]=T_P0[i]; }
  __syncthreads();
  int wave = threadIdx.x>>6, lane = threadIdx.x&63;
  int node = blockIdx.x*4 + wave;
  float wv0[NBESS], wv1[NBESS];
  #pragma unroll
  for (int n=0;n<NBESS;n++){ wv0[n]=Wrad[n*HD+lane]; wv1[n]=Wrad[n*HD+64+lane]; }
  int b = rp[node], en = rp[node+1];
  float acc0 = 0.f, acc1 = 0.f;
  int i = b;
  for (; i+4 <= en; i+=4){
    const float* g0=geom+(size_t)(i+0)*GS; const float* g1=geom+(size_t)(i+1)*GS;
    const float* g2=geom+(size_t)(i+2)*GS; const float* g3=geom+(size_t)(i+3)*GS;
    float4 ra0=*(const float4*)(g0+4), rb0=*(const float4*)(g0+8);
    float4 ra1=*(const float4*)(g1+4), rb1=*(const float4*)(g1+8);
    float4 ra2=*(const float4*)(g2+4), rb2=*(const float4*)(g2+8);
    float4 ra3=*(const float4*)(g3+4), rb3=*(const float4*)(g3+8);
    float s0=g0[12], s1=g1[12], s2=g2[12], s3=g3[12];
    int sp0=__float_as_int(g0[14])>>15, sp1=__float_as_int(g1[14])>>15;
    int sp2=__float_as_int(g2[14])>>15, sp3=__float_as_int(g3[14])>>15;
    acc0 += tp[sp0*TPS+lane]*(s0*dot8(ra0,rb0,wv0));  acc1 += tp[sp0*TPS+64+lane]*(s0*dot8(ra0,rb0,wv1));
    acc0 += tp[sp1*TPS+lane]*(s1*dot8(ra1,rb1,wv0));  acc1 += tp[sp1*TPS+64+lane]*(s1*dot8(ra1,rb1,wv1));
    acc0 += tp[sp2*TPS+lane]*(s2*dot8(ra2,rb2,wv0));  acc1 += tp[sp2*TPS+64+lane]*(s2*dot8(ra2,rb2,wv1));
    acc0 += tp[sp3*TPS+lane]*(s3*dot8(ra3,rb3,wv0));  acc1 += tp[sp3*TPS+64+lane]*(s3*dot8(ra3,rb3,wv1));
  }
  for (; i<en; i++){
    const float* g = geom + (size_t)i*GS;
    float4 ra = *(const float4*)(g+4);
    float4 rb = *(const float4*)(g+8);
    float shs = g[12];
    int sp = __float_as_int(g[14]) >> 15;
    acc0 += tp[sp*TPS+lane]    * (shs*dot8(ra,rb,wv0));
    acc1 += tp[sp*TPS+64+lane] * (shs*dot8(ra,rb,wv1));
  }
  out[(size_t)node*HD+lane]    = acc0;
  out[(size_t)node*HD+64+lane] = acc1;
}

// ---------------- layer-1 dst gather (P1 rows random), 4x unroll; src from geom ----------------
__global__ __launch_bounds__(256) void gatherD_k(const float* __restrict__ geom,
        const int* __restrict__ rp,
        const float* __restrict__ rows,
        const float* __restrict__ Wrad, int shsOff, float* __restrict__ out){
  int wave = threadIdx.x>>6, lane = threadIdx.x&63;
  int node = blockIdx.x*4 + wave;
  float wv0[NBESS], wv1[NBESS];
  #pragma unroll
  for (int n=0;n<NBESS;n++){ wv0[n]=Wrad[n*HD+lane]; wv1[n]=Wrad[n*HD+64+lane]; }
  int b = rp[node], en = rp[node+1];
  float acc0 = 0.f, acc1 = 0.f;
  int i = b;
  for (; i+4 <= en; i+=4){
    const float* g0=geom+(size_t)(i+0)*GS; const float* g1=geom+(size_t)(i+1)*GS;
    const float* g2=geom+(size_t)(i+2)*GS; const float* g3=geom+(size_t)(i+3)*GS;
    int o0=__float_as_int(g0[14])&0x7FFF, o1=__float_as_int(g1[14])&0x7FFF;
    int o2=__float_as_int(g2[14])&0x7FFF, o3=__float_as_int(g3[14])&0x7FFF;
    float4 ra0=*(const float4*)(g0+4), rb0=*(const float4*)(g0+8);
    float4 ra1=*(const float4*)(g1+4), rb1=*(const float4*)(g1+8);
    float4 ra2=*(const float4*)(g2+4), rb2=*(const float4*)(g2+8);
    float4 ra3=*(const float4*)(g3+4), rb3=*(const float4*)(g3+8);
    float s0=g0[shsOff], s1=g1[shsOff], s2=g2[shsOff], s3=g3[shsOff];
    float p00=rows[(size_t)o0*HD+lane], p01=rows[(size_t)o0*HD+64+lane];
    float p10=rows[(size_t)o1*HD+lane], p11=rows[(size_t)o1*HD+64+lane];
    float p20=rows[(size_t)o2*HD+lane], p21=rows[(size_t)o2*HD+64+lane];
    float p30=rows[(size_t)o3*HD+lane], p31=rows[(size_t)o3*HD+64+lane];
    acc0 += p00*(s0*dot8(ra0,rb0,wv0));  acc1 += p01*(s0*dot8(ra0,rb0,wv1));
    acc0 += p10*(s1*dot8(ra1,rb1,wv0));  acc1 += p11*(s1*dot8(ra1,rb1,wv1));
    acc0 += p20*(s2*dot8(ra2,rb2,wv0));  acc1 += p21*(s2*dot8(ra2,rb2,wv1));
    acc0 += p30*(s3*dot8(ra3,rb3,wv0));  acc1 += p31*(s3*dot8(ra3,rb3,wv1));
  }
  for (; i<en; i++){
    const float* g = geom + (size_t)i*GS;
    int o = __float_as_int(g[14])&0x7FFF;
    float4 ra = *(const float4*)(g+4);
    float4 rb = *(const float4*)(g+8);
    float shs = g[shsOff];
    acc0 += rows[(size_t)o*HD+lane]    * (shs*dot8(ra,rb,wv0));
    acc1 += rows[(size_t)o*HD+64+lane] * (shs*dot8(ra,rb,wv1));
  }
  out[(size_t)node*HD+lane]    = acc0;
  out[(size_t)node*HD+64+lane] = acc1;
}

// ---------------- src-keyed gather (backward A1), 4x unroll ----------------
__global__ __launch_bounds__(256) void gatherS_k(const float* __restrict__ geom,
        const int* __restrict__ rp, const int2* __restrict__ pdS,
        const float* __restrict__ rows,
        const float* __restrict__ Wrad, int shsOff, float* __restrict__ out){
  int wave = threadIdx.x>>6, lane = threadIdx.x&63;
  int node = blockIdx.x*4 + wave;
  float wv0[NBESS], wv1[NBESS];
  #pragma unroll
  for (int n=0;n<NBESS;n++){ wv0[n]=Wrad[n*HD+lane]; wv1[n]=Wrad[n*HD+64+lane]; }
  int b = rp[node], en = rp[node+1];
  float acc0 = 0.f, acc1 = 0.f;
  int i = b;
  for (; i+4 <= en; i+=4){
    int2 t0=pdS[i+0], t1=pdS[i+1], t2=pdS[i+2], t3=pdS[i+3];
    const float* g0=geom+(size_t)t0.x*GS; const float* g1=geom+(size_t)t1.x*GS;
    const float* g2=geom+(size_t)t2.x*GS; const float* g3=geom+(size_t)t3.x*GS;
    float4 ra0=*(const float4*)(g0+4), rb0=*(const float4*)(g0+8);
    float4 ra1=*(const float4*)(g1+4), rb1=*(const float4*)(g1+8);
    float4 ra2=*(const float4*)(g2+4), rb2=*(const float4*)(g2+8);
    float4 ra3=*(const float4*)(g3+4), rb3=*(const float4*)(g3+8);
    float s0=g0[shsOff], s1=g1[shsOff], s2=g2[shsOff], s3=g3[shsOff];
    float p00=rows[(size_t)t0.y*HD+lane], p01=rows[(size_t)t0.y*HD+64+lane];
    float p10=rows[(size_t)t1.y*HD+lane], p11=rows[(size_t)t1.y*HD+64+lane];
    float p20=rows[(size_t)t2.y*HD+lane], p21=rows[(size_t)t2.y*HD+64+lane];
    float p30=rows[(size_t)t3.y*HD+lane], p31=rows[(size_t)t3.y*HD+64+lane];
    acc0 += p00*(s0*dot8(ra0,rb0,wv0));  acc1 += p01*(s0*dot8(ra0,rb0,wv1));
    acc0 += p10*(s1*dot8(ra1,rb1,wv0));  acc1 += p11*(s1*dot8(ra1,rb1,wv1));
    acc0 += p20*(s2*dot8(ra2,rb2,wv0));  acc1 += p21*(s2*dot8(ra2,rb2,wv1));
    acc0 += p30*(s3*dot8(ra3,rb3,wv0));  acc1 += p31*(s3*dot8(ra3,rb3,wv1));
  }
  for (; i<en; i++){
    int2 t = pdS[i];
    const float* g = geom + (size_t)t.x*GS;
    float4 ra = *(const float4*)(g+4);
    float4 rb = *(const float4*)(g+8);
    float shs = g[shsOff];
    acc0 += rows[(size_t)t.y*HD+lane]    * (shs*dot8(ra,rb,wv0));
    acc1 += rows[(size_t)t.y*HD+64+lane] * (shs*dot8(ra,rb,wv1));
  }
  out[(size_t)node*HD+lane]    = acc0;
  out[(size_t)node*HD+64+lane] = acc1;
}

// ---------------- fused two-layer qdot; weights in LDS; indices from geom ----------------
__global__ __launch_bounds__(256) void qdotF_k(const float* __restrict__ geom,
        const float* __restrict__ G1, const float* __restrict__ P1,
        const float* __restrict__ G0, const float* __restrict__ T_P0,
        const float* __restrict__ Wrad, const float* __restrict__ wshp,
        float* __restrict__ gvec){
  __shared__ float wr0[NBESS*HD];
  __shared__ float wr1[NBESS*HD];
  __shared__ float tp0[NZ*TPS];
  __shared__ float ws[18];
  for (int i=threadIdx.x; i<NBESS*HD; i+=256){ wr0[i]=Wrad[i]; wr1[i]=Wrad[NBESS*HD+i]; }
  for (int i=threadIdx.x; i<NZ*HD; i+=256){ int z=i>>7, h=i&127; tp0[z*TPS+h]=T_P0[i]; }
  if (threadIdx.x < 18) ws[threadIdx.x] = wshp[threadIdx.x];
  __syncthreads();
  int i = blockIdx.x*256+threadIdx.x;
  const float* g = geom + (size_t)i*GS;
  int g14 = __float_as_int(g[14]);
  int s = g14 & 0x7FFF, sp = g14 >> 15;
  int d = __float_as_int(g[15]);
  const float4* G1r = (const float4*)(G1 + (size_t)d*HD);
  const float4* P1r = (const float4*)(P1 + (size_t)s*HD);
  const float4* G0r = (const float4*)(G0 + (size_t)d*HD);
  const float* P0l = tp0 + sp*TPS;
  float gr80[NBESS] = {0,0,0,0,0,0,0,0};
  float gr81[NBESS] = {0,0,0,0,0,0,0,0};
  #pragma unroll 2
  for (int k=0; k<32; k++){
    float4 g1q = G1r[k], p1q = P1r[k];
    float4 g0q = G0r[k];
    float4 p0q = *(const float4*)&P0l[4*k];
    float a0 = g1q.x*p1q.x, a1 = g1q.y*p1q.y, a2 = g1q.z*p1q.z, a3 = g1q.w*p1q.w;
    float b0 = g0q.x*p0q.x, b1 = g0q.y*p0q.y, b2 = g0q.z*p0q.z, b3 = g0q.w*p0q.w;
    #pragma unroll
    for (int n=0; n<NBESS; n++){
      const float4 w1 = *(const float4*)&wr1[n*HD + 4*k];
      const float4 w0 = *(const float4*)&wr0[n*HD + 4*k];
      gr81[n] += a0*w1.x + a1*w1.y + a2*w1.z + a3*w1.w;
      gr80[n] += b0*w0.x + b1*w0.y + b2*w0.z + b3*w0.w;
    }
  }
  float vx=g[0], vy=g[1], vz=g[2], r=g[3];
  float shs0 = g[12], shs1 = g[13];
  float gshs0 = 0.f, gshs1 = 0.f;
  float grd[NBESS];
  #pragma unroll
  for (int n=0; n<NBESS; n++){
    float rn = g[4+n];
    gshs0 += rn*gr80[n];
    gshs1 += rn*gr81[n];
    grd[n] = shs0*gr80[n] + shs1*gr81[n];
  }
  float inv = 1.0f/r;
  float x = vx*inv, y = vy*inv, z = vz*inv;
  float gs1=gshs0*ws[1]+gshs1*ws[10], gs2=gshs0*ws[2]+gshs1*ws[11];
  float gs3=gshs0*ws[3]+gshs1*ws[12], gs4=gshs0*ws[4]+gshs1*ws[13];
  float gs5=gshs0*ws[5]+gshs1*ws[14], gs6=gshs0*ws[6]+gshs1*ws[15];
  float gs7=gshs0*ws[7]+gshs1*ws[16], gs8=gshs0*ws[8]+gshs1*ws[17];
  float gux = SH_C1*gs3 + SH_C2*(y*gs4 + z*gs7) + 1.0925484306f*x*gs8;
  float guy = SH_C1*gs1 + SH_C2*(x*gs4 + z*gs5) - 1.0925484306f*y*gs8;
  float guz = SH_C1*gs2 + SH_C2*(y*gs5 + x*gs7) + 1.8923493918f*z*gs6;
  float udot = x*gux + y*guy + z*guz;
  float gr = 0.f;
  if (r < RMAXF){
    float theta = PI_F*r/RMAXF;
    float s1 = sinf(theta), c1 = cosf(theta);
    float env  = 0.5f*(c1+1.0f);
    float denv = -0.5f*(PI_F/RMAXF)*s1;
    float sn = s1, cn = c1;
    #pragma unroll
    for (int n=0; n<NBESS; n++){
      float an = (float)(n+1)*(PI_F/RMAXF);
      float bess  = C_PREF*sn*inv;
      float dbess = C_PREF*inv*(an*cn - sn*inv);
      gr += grd[n]*(dbess*env + bess*denv);
      float sn2 = sn*c1 + cn*s1;
      float cn2 = cn*c1 - sn*s1;
      sn = sn2; cn = cn2;
    }
  }
  gvec[3*(size_t)i+0] = gr*x + (gux - x*udot)*inv;
  gvec[3*(size_t)i+1] = gr*y + (guy - y*udot)*inv;
  gvec[3*(size_t)i+2] = gr*z + (guz - z*udot)*inv;
}

// ---------------- F[n] = sum_out gvec - sum_in gvec (gvec at dst-CSR pos) ----------------
__global__ __launch_bounds__(256) void fgather_k(const int* __restrict__ rpd,
        const int* __restrict__ rps, const int2* __restrict__ pdS,
        const float* __restrict__ gvec, float* __restrict__ F){
  int wave = threadIdx.x>>6, lane = threadIdx.x&63;
  int n = blockIdx.x*4 + wave;
  float fx=0.f, fy=0.f, fz=0.f;
  int b=rps[n], en=rps[n+1];
  for (int i=b+lane; i<en; i+=64){ int j=pdS[i].x; fx+=gvec[3*(size_t)j]; fy+=gvec[3*(size_t)j+1]; fz+=gvec[3*(size_t)j+2]; }
  b=rpd[n]; en=rpd[n+1];
  for (int i=b+lane; i<en; i+=64){ fx-=gvec[3*(size_t)i]; fy-=gvec[3*(size_t)i+1]; fz-=gvec[3*(size_t)i+2]; }
  #pragma unroll
  for (int off=1; off<64; off<<=1){
    fx += __shfl_xor(fx, off);
    fy += __shfl_xor(fy, off);
    fz += __shfl_xor(fz, off);
  }
  if (lane==0){ F[3*(size_t)n]=fx; F[3*(size_t)n+1]=fy; F[3*(size_t)n+2]=fz; }
}

extern "C" void kernel_launch(void* const* d_in, const int* in_sizes, int n_in,
                              void* d_out, int out_size, void* d_ws, size_t ws_size,
                              hipStream_t stream){
  const float* pos    = (const float*)d_in[0];
  const float* attrs  = (const float*)d_in[1];
  const float* shifts = (const float*)d_in[2];
  const float* Wemb   = (const float*)d_in[4];
  const float* Wmsg   = (const float*)d_in[5];
  const float* Wrad   = (const float*)d_in[6];
  const float* wsh    = (const float*)d_in[7];
  const float* Wprod  = (const float*)d_in[8];
  const float* Wsc    = (const float*)d_in[9];
  const float* Wread  = (const float*)d_in[10];
  const float* scalep = (const float*)d_in[11];
  const int*   eidx   = (const int*)d_in[13];
  const int* srcI = eidx;
  const int* dstI = eidx + N_EDGES;
  float* F = (float*)d_out;
  (void)ws_size; (void)in_sizes; (void)n_in; (void)out_size;

  float* w = (float*)d_ws;
  size_t off = 0;
  auto alloc = [&](size_t nf){ float* p = w + off; off += nf; return p; };
  float* geom = alloc((size_t)N_EDGES*GS);
  float* h1   = alloc(NH);
  float* P1   = alloc(NH);
  float* z0   = alloc(NH);
  float* z1   = alloc(NH);
  float* Svar = alloc(NH);
  float* agg  = alloc(NH);
  float* Gbuf1= alloc(NH);
  float* Gbuf0= alloc(NH);
  float* A1   = alloc(NH);
  float* gh1  = alloc(NH);
  float* T_P0 = alloc(NZ*HD);
  float* T_sc = alloc(NZ*HD);
  float* g2vec = alloc(HD);
  float* gh1c  = alloc(HD);
  float* gvec  = alloc((size_t)N_EDGES*3);
  unsigned short* Wb = (unsigned short*)alloc(6*HH);
  int* ibase = (int*)(w + off);
  int* cnt2 = ibase;                        // 2*N
  int* rp2  = ibase + 2*N_NODES;            // 2*(N+1)
  int* cur2 = rp2 + 2*(N_NODES+1);          // 2*(N+1)
  int* spec = cur2 + 2*(N_NODES+1);         // N
  int2* pdS = (int2*)(((size_t)(spec + N_NODES) + 7) & ~(size_t)7); // E int2
  int* rpd = rp2;
  int* rps = rp2 + (N_NODES+1);
  int* curd = cur2;
  int* curs = cur2 + (N_NODES+1);

  const unsigned short* Wp0T_h = Wb + 0*HH; const unsigned short* Wp0T_l = Wb + 1*HH;
  const unsigned short* Wp0R_h = Wb + 2*HH; const unsigned short* Wp0R_l = Wb + 3*HH;
  const unsigned short* Wp1T_h = Wb + 4*HH; const unsigned short* Wp1T_l = Wb + 5*HH;
  const unsigned short* Wp1R_h = Wb + 6*HH; const unsigned short* Wp1R_l = Wb + 7*HH;
  const unsigned short* Wm1T_h = Wb + 8*HH; const unsigned short* Wm1T_l = Wb + 9*HH;
  const unsigned short* Wm1R_h = Wb +10*HH; const unsigned short* Wm1R_l = Wb +11*HH;

  const int GEMM_GRID = N_NODES/32;    // 625
  const int NODE_GRID = N_NODES/4;     // 5000
  const int E_GRID    = N_EDGES/256;   // 2500

  // CSR build
  zeroi_k<<<(2*N_NODES+255)/256, 256, 0, stream>>>(cnt2, 2*N_NODES);
  hist_k<<<E_GRID, 256, 0, stream>>>(srcI, dstI, cnt2, cnt2+N_NODES);
  scan_k<<<2, 1024, 0, stream>>>(cnt2, rp2);
  cpyi_k<<<(2*(N_NODES+1)+255)/256, 256, 0, stream>>>(rp2, cur2, 2*(N_NODES+1));

  species_k<<<(N_NODES+255)/256, 256, 0, stream>>>(attrs, spec);
  geom_k<<<E_GRID, 256, 0, stream>>>(pos, shifts, srcI, dstI, curd, curs, pdS, spec, wsh, geom);
  tables_k<<<NZ, HD, 0, stream>>>(Wemb, Wmsg, Wsc, T_P0, T_sc);
  wprep_k<<<(3*HH+255)/256, 256, 0, stream>>>(Wprod, Wmsg, (unsigned short*)Wb);
  consts_k<<<1, HD, 0, stream>>>(Wread, Wsc, scalep, g2vec, gh1c);

  // ---- layer 0 forward (P0/sc0 via species tables) ----
  gatherD0_k<<<NODE_GRID, 256, 0, stream>>>(geom, rpd, T_P0, Wrad, agg);
  gemmM_k<<<GEMM_GRID, 256, 0, stream>>>(agg, Wp0T_h, Wp0T_l, z0, nullptr);
  h1_k<<<NH/256, 256, 0, stream>>>(z0, spec, T_sc, h1);

  // ---- layer 1 forward ----
  gemmM_k<<<GEMM_GRID, 256, 0, stream>>>(h1, Wm1T_h, Wm1T_l, P1, nullptr);
  gatherD_k<<<NODE_GRID, 256, 0, stream>>>(geom, rpd, P1, Wrad+NBESS*HD, 13, agg);
  gemmM_k<<<GEMM_GRID, 256, 0, stream>>>(agg, Wp1T_h, Wp1T_l, z1, nullptr);

  // ---- backward ----
  dzb_k<<<NH/256, 256, 0, stream>>>(z1, g2vec, Svar);
  gemmM_k<<<GEMM_GRID, 256, 0, stream>>>(Svar, Wp1R_h, Wp1R_l, Gbuf1, nullptr);
  gatherS_k<<<NODE_GRID, 256, 0, stream>>>(geom, rps, pdS, Gbuf1, Wrad+NBESS*HD, 13, A1);
  gemmM_k<<<GEMM_GRID, 256, 0, stream>>>(A1, Wm1R_h, Wm1R_l, gh1, gh1c);
  dzf_k<<<NH/256, 256, 0, stream>>>(z0, gh1, Svar);
  gemmM_k<<<GEMM_GRID, 256, 0, stream>>>(Svar, Wp0R_h, Wp0R_l, Gbuf0, nullptr);
  qdotF_k<<<E_GRID, 256, 0, stream>>>(geom, Gbuf1, P1, Gbuf0, T_P0, Wrad, wsh, gvec);
  fgather_k<<<NODE_GRID, 256, 0, stream>>>(rpd, rps, pdS, gvec, F);
}